// Round 2
// baseline (8809.466 us; speedup 1.0000x reference)
//
#include <hip/hip_runtime.h>

#define B 16
#define D 256
#define T 4096
#define NQ 8
#define BINS 1024
#define TOK 32        // tokens per block
#define RS 260        // LDS row stride (floats): float4-aligned, 2-way-max bank pattern
#define EPS 0.02f     // certified f32-scan margin; below this -> exact f64 fallback

#define OFF_C  ((size_t)B * D * T)            // quantized elems = 16777216
#define OFF_BW (OFF_C + (size_t)NQ * B * T)   // + codes 524288 -> 17301504
#define OFF_L  (OFF_BW + 1)

// ---------------- codebook norms: f64 (exact fallback) + f32 (scan) ----------------
__global__ __launch_bounds__(256) void cbnorm_kernel(const float* __restrict__ cb,
                                                     double* __restrict__ cbn,
                                                     float* __restrict__ cbnf)
{
    const int wave = threadIdx.x >> 6;
    const int lane = threadIdx.x & 63;
    const int bin = blockIdx.x * 4 + wave;          // 0..8191 (q*1024+k)
    const float4 v = *(const float4*)&cb[(size_t)bin * D + lane * 4];
    double a = (double)v.x * v.x + (double)v.y * v.y
             + (double)v.z * v.z + (double)v.w * v.w;
    #pragma unroll
    for (int off = 32; off >= 1; off >>= 1)
        a += __shfl_xor(a, off, 64);
    if (lane == 0) { cbn[bin] = a; cbnf[bin] = (float)a; }
}

// ---------------- fused RVQ: all 8 stages per token tile ----------------
__global__ __launch_bounds__(256, 3) void rvq_main(
    const float* __restrict__ x, const float* __restrict__ cb,
    const double* __restrict__ cbn, const float* __restrict__ cbnf,
    float* __restrict__ out, double* __restrict__ lpart)
{
    __shared__ float  res[TOK][RS];
    __shared__ float  bv1s[TOK][16];
    __shared__ float  bv2s[TOK][16];
    __shared__ int    bi1s[TOK][16];
    __shared__ int    idxs[TOK];
    __shared__ int    flags[TOK];
    __shared__ double fbv[256];      // fallback reduce + final loss reduce
    __shared__ int    fbi[256];

    const int tid = threadIdx.x;
    const int bid = blockIdx.x;
    const int b  = bid >> 7;              // / (T/TOK) = /128
    const int t0 = (bid & 127) * TOK;

    // load x tile [32 tok][256 d] (coalesced 128B segments along t)
    const float* xb = x + (size_t)b * D * T + t0;
    #pragma unroll
    for (int it = 0; it < 32; ++it) {
        const int d  = it * 8 + (tid >> 5);
        const int tk = tid & 31;
        res[tk][d] = xb[(size_t)d * T + tk];
    }
    __syncthreads();

    // per-thread quantized accumulator: token tid>>3, dims (tid&7)*32 .. +31
    float qreg[32];
    #pragma unroll
    for (int i = 0; i < 32; ++i) qreg[i] = 0.0f;

    const int tg = tid & 15;   // token group: owns tokens tg and tg+16
    const int bg = tid >> 4;   // bin group 0..15 (8 bins per chunk)
    const int tku = tid >> 3;  // update/out token
    const int d0u = (tid & 7) * 32;
    double lacc = 0.0;

    for (int q = 0; q < NQ; ++q) {
        const float*  cbq = cb   + (size_t)q * BINS * D;
        const float*  cnf = cbnf + (size_t)q * BINS;
        const double* cnd = cbn  + (size_t)q * BINS;

        float bvA = 3.4e38f, bvA2 = 3.4e38f;  int biA = 0;
        float bvB = 3.4e38f, bvB2 = 3.4e38f;  int biB = 0;

        for (int iter = 0; iter < 8; ++iter) {
            const int binbase = iter * 128 + bg * 8;
            float a0[8], a1[8];
            #pragma unroll
            for (int j = 0; j < 8; ++j) { a0[j] = 0.0f; a1[j] = 0.0f; }

            for (int d = 0; d < D; d += 4) {
                const float4 r0 = *(const float4*)&res[tg][d];
                const float4 r1 = *(const float4*)&res[tg + 16][d];
                #pragma unroll
                for (int j = 0; j < 8; ++j) {
                    const float4 c = *(const float4*)&cbq[(size_t)(binbase + j) * D + d];
                    a0[j] = fmaf(r0.x, c.x, a0[j]); a0[j] = fmaf(r0.y, c.y, a0[j]);
                    a0[j] = fmaf(r0.z, c.z, a0[j]); a0[j] = fmaf(r0.w, c.w, a0[j]);
                    a1[j] = fmaf(r1.x, c.x, a1[j]); a1[j] = fmaf(r1.y, c.y, a1[j]);
                    a1[j] = fmaf(r1.z, c.z, a1[j]); a1[j] = fmaf(r1.w, c.w, a1[j]);
                }
            }
            #pragma unroll
            for (int j = 0; j < 8; ++j) {
                const int bin = binbase + j;
                const float qn = cnf[bin];
                const float s0 = fmaf(-2.0f, a0[j], qn);   // dist - ||r||^2 (const/token)
                const float s1 = fmaf(-2.0f, a1[j], qn);
                if (s0 < bvA) { bvA2 = bvA; bvA = s0; biA = bin; }
                else if (s0 < bvA2) { bvA2 = s0; }
                if (s1 < bvB) { bvB2 = bvB; bvB = s1; biB = bin; }
                else if (s1 < bvB2) { bvB2 = s1; }
            }
        }
        bv1s[tg][bg]      = bvA;  bv2s[tg][bg]      = bvA2;  bi1s[tg][bg]      = biA;
        bv1s[tg + 16][bg] = bvB;  bv2s[tg + 16][bg] = bvB2;  bi1s[tg + 16][bg] = biB;
        __syncthreads();

        // per-token top-2 merge across 16 bin-groups, lowest-index tie-break
        if (tid < TOK) {
            float g1 = bv1s[tid][0], g2 = bv2s[tid][0];
            int   gi = bi1s[tid][0];
            #pragma unroll
            for (int g = 1; g < 16; ++g) {
                const float v1 = bv1s[tid][g];
                const float v2 = bv2s[tid][g];
                const int   i1 = bi1s[tid][g];
                if (v1 < g1 || (v1 == g1 && i1 < gi)) {
                    g2 = fminf(g1, v2); g1 = v1; gi = i1;
                } else {
                    g2 = fminf(g2, v1);
                }
            }
            idxs[tid]  = gi;
            flags[tid] = (g2 - g1 < EPS) ? 1 : 0;
        }
        __syncthreads();

        // exact f64 fallback for near-tie tokens (rare)
        for (int tok = 0; tok < TOK; ++tok) {
            if (!flags[tok]) continue;               // uniform branch (LDS)
            double bb = 1e300; int bbi = 0;
            #pragma unroll
            for (int jj = 0; jj < 4; ++jj) {
                const int bin = tid + 256 * jj;      // ascending -> lowest-idx tie keep
                const float* crow = cbq + (size_t)bin * D;
                double a = 0.0;
                for (int d = 0; d < D; d += 4) {
                    const float4 r = *(const float4*)&res[tok][d];  // broadcast
                    const float4 c = *(const float4*)&crow[d];
                    a = fma((double)r.x, (double)c.x, a);
                    a = fma((double)r.y, (double)c.y, a);
                    a = fma((double)r.z, (double)c.z, a);
                    a = fma((double)r.w, (double)c.w, a);
                }
                const double s = fma(-2.0, a, cnd[bin]);
                if (s < bb) { bb = s; bbi = bin; }
            }
            fbv[tid] = bb; fbi[tid] = bbi;
            __syncthreads();
            for (int s2 = 128; s2 >= 1; s2 >>= 1) {
                if (tid < s2) {
                    const double ov = fbv[tid + s2]; const int oi = fbi[tid + s2];
                    const double mv = fbv[tid];      const int mi = fbi[tid];
                    if (ov < mv || (ov == mv && oi < mi)) { fbv[tid] = ov; fbi[tid] = oi; }
                }
                __syncthreads();
            }
            if (tid == 0) idxs[tok] = fbi[0];
            __syncthreads();
        }

        // write codes
        if (tid < TOK)
            out[OFF_C + (size_t)q * B * T + (size_t)b * T + t0 + tid] = (float)idxs[tid];

        // faithful straight-through update: e=q-r; qst=r+e; r-=qst; quant+=qst
        const float* crow = cbq + (size_t)idxs[tku] * D;
        #pragma unroll
        for (int i = 0; i < 8; ++i) {
            const int d = d0u + i * 4;
            const float4 qv = *(const float4*)&crow[d];
            float4 r = *(float4*)&res[tku][d];
            float e, qst, dd;
            e = qv.x - r.x; qst = r.x + e; dd = qst - r.x;
            lacc = fma((double)dd, (double)dd, lacc); qreg[i*4+0] += qst; r.x = r.x - qst;
            e = qv.y - r.y; qst = r.y + e; dd = qst - r.y;
            lacc = fma((double)dd, (double)dd, lacc); qreg[i*4+1] += qst; r.y = r.y - qst;
            e = qv.z - r.z; qst = r.z + e; dd = qst - r.z;
            lacc = fma((double)dd, (double)dd, lacc); qreg[i*4+2] += qst; r.z = r.z - qst;
            e = qv.w - r.w; qst = r.w + e; dd = qst - r.w;
            lacc = fma((double)dd, (double)dd, lacc); qreg[i*4+3] += qst; r.w = r.w - qst;
            *(float4*)&res[tku][d] = r;
        }
        __syncthreads();
    }

    // res is dead: stage qreg through it for coalesced [B,D,T] stores
    #pragma unroll
    for (int i = 0; i < 8; ++i)
        *(float4*)&res[tku][d0u + i * 4] = *(float4*)&qreg[i * 4];
    __syncthreads();
    #pragma unroll
    for (int it = 0; it < 32; ++it) {
        const int d  = it * 8 + (tid >> 5);
        const int tk = tid & 31;
        out[(size_t)b * D * T + (size_t)d * T + t0 + tk] = res[tk][d];
    }

    // deterministic per-block loss partial
    fbv[tid] = lacc;
    __syncthreads();
    for (int s2 = 128; s2 >= 1; s2 >>= 1) {
        if (tid < s2) fbv[tid] += fbv[tid + s2];
        __syncthreads();
    }
    if (tid == 0) lpart[bid] = fbv[0];
}

// ---------------- finalize: loss mean + bandwidth scalar ----------------
__global__ __launch_bounds__(256) void finalize_kernel(
    const double* __restrict__ lpart, int nblk,
    const int* __restrict__ srp, float* __restrict__ out)
{
    __shared__ double sh[256];
    double a = 0.0;
    for (int i = threadIdx.x; i < nblk; i += 256) a += lpart[i];
    sh[threadIdx.x] = a;
    __syncthreads();
    for (int s = 128; s >= 1; s >>= 1) {
        if (threadIdx.x < s) sh[threadIdx.x] += sh[threadIdx.x + s];
        __syncthreads();
    }
    if (threadIdx.x == 0) {
        out[OFF_L]  = (float)(sh[0] / ((double)NQ * B * T * D));
        out[OFF_BW] = (float)((double)NQ * 10.0 * (double)srp[0] / 1000.0);
    }
}

extern "C" void kernel_launch(void* const* d_in, const int* in_sizes, int n_in,
                              void* d_out, int out_size, void* d_ws, size_t ws_size,
                              hipStream_t stream)
{
    const float* x  = (const float*)d_in[0];
    const float* cb = (const float*)d_in[1];
    const int*   sr = (const int*)d_in[2];
    float* out = (float*)d_out;
    double* cbn   = (double*)d_ws;                    // 8192 doubles
    float*  cbnf  = (float*)(cbn + NQ * BINS);        // 8192 floats
    double* lpart = (double*)(cbnf + NQ * BINS);      // 2048 doubles

    hipLaunchKernelGGL(cbnorm_kernel, dim3(NQ * BINS / 4), dim3(256), 0, stream, cb, cbn, cbnf);
    hipLaunchKernelGGL(rvq_main, dim3(B * (T / TOK)), dim3(256), 0, stream, x, cb, cbn, cbnf, out, lpart);
    hipLaunchKernelGGL(finalize_kernel, dim3(1), dim3(256), 0, stream,
                       lpart, B * (T / TOK), sr, out);
}

// Round 3
// 5199.422 us; speedup vs baseline: 1.6943x; 1.6943x over previous
//
#include <hip/hip_runtime.h>

#define B 16
#define D 256
#define T 4096
#define NQ 8
#define BINS 1024

#define OFF_C  ((size_t)B * D * T)            // quantized elems = 16777216
#define OFF_BW (OFF_C + (size_t)NQ * B * T)   // + codes 524288 -> 17301504
#define OFF_L  (OFF_BW + 1)

typedef __attribute__((ext_vector_type(8))) short short8v;
typedef __attribute__((ext_vector_type(4))) float float4v;

__device__ __forceinline__ unsigned short f2bf(float f) {
    unsigned u = __float_as_uint(f);
    unsigned r = (u + 0x7fffu + ((u >> 16) & 1u)) >> 16;   // RNE
    return (unsigned short)r;
}
__device__ __forceinline__ float bf2f(unsigned short h) {
    return __uint_as_float(((unsigned)h) << 16);
}

// ---------------- codebook norms: f64 (exact fallback) + f32 (scan) ----------------
__global__ __launch_bounds__(256) void cbnorm_kernel(const float* __restrict__ cb,
                                                     double* __restrict__ cbn,
                                                     float* __restrict__ cbnf)
{
    const int wave = threadIdx.x >> 6;
    const int lane = threadIdx.x & 63;
    const int bin = blockIdx.x * 4 + wave;          // 0..8191 (q*1024+k)
    const float4 v = *(const float4*)&cb[(size_t)bin * D + lane * 4];
    double a = (double)v.x * v.x + (double)v.y * v.y
             + (double)v.z * v.z + (double)v.w * v.w;
    #pragma unroll
    for (int off = 32; off >= 1; off >>= 1)
        a += __shfl_xor(a, off, 64);
    if (lane == 0) { cbn[bin] = a; cbnf[bin] = (float)a; }
}

// ---------------- prep: codebook -> bf16 hi/lo planes in MFMA-B-fragment order ----
// combo c = (q*64 + ntg)*8 + ks ; element: lane l, j -> B[k=ks*32+(l>>4)*8+j][n=ntg*16+(l&15)]
__global__ __launch_bounds__(256) void prep_bfrag(const float* __restrict__ cb,
                                                  unsigned short* __restrict__ bfh,
                                                  unsigned short* __restrict__ bfl)
{
    const int c = blockIdx.x * 4 + (threadIdx.x >> 6);   // 0..4095
    const int lane = threadIdx.x & 63;
    const int q = c >> 9, ntg = (c >> 3) & 63, ks = c & 7;
    const float* src = cb + ((size_t)q * BINS + ntg * 16 + (lane & 15)) * D
                         + ks * 32 + (lane >> 4) * 8;
    short8v h, l;
    #pragma unroll
    for (int j = 0; j < 8; ++j) {
        const float v = src[j];
        const unsigned short hh = f2bf(v);
        h[j] = (short)hh;
        l[j] = (short)f2bf(v - bf2f(hh));
    }
    const size_t off = ((size_t)c * 64 + lane) * 8;
    *(short8v*)(bfh + off) = h;
    *(short8v*)(bfl + off) = l;
}

// ---------------- main: fused 8-stage RVQ via split-bf16 MFMA ----------------
// 64 tokens/block, 4 waves; wave w scans bins [w*256, w*256+256).
// SMEM layout (bytes):
//  0      : union { A_hi[64][256]bf16 @0 (swz), A_lo @32768 | resf f32[64][257] } = 65792
//  65792  : norms f32[1024]
//  69888  : mg1 f32[256]; 70912: mg2 f32[256]; 71936: mgi int[256]
//  72960  : idxsL int[64]; 73216: flagsL int[64]
//  73472  : fbres f32[256]
//  74496  : redv double[256]; 76544: redi int[256]   -> total 77568
__global__ __launch_bounds__(256, 2) void rvq_mfma(
    const float* __restrict__ x, const float* __restrict__ cb,
    const double* __restrict__ cbn, const float* __restrict__ cbnf,
    const unsigned short* __restrict__ bfh, const unsigned short* __restrict__ bfl,
    float* __restrict__ out, double* __restrict__ lpart)
{
    __shared__ __align__(16) char smem[77568];
    char*   smc   = smem;
    float*  resf  = (float*)smem;
    float*  norms = (float*)(smem + 65792);
    float*  mg1   = (float*)(smem + 69888);
    float*  mg2   = (float*)(smem + 70912);
    int*    mgi   = (int*)(smem + 71936);
    int*    idxsL = (int*)(smem + 72960);
    int*    flagsL= (int*)(smem + 73216);
    float*  fbres = (float*)(smem + 73472);
    double* redv  = (double*)(smem + 74496);
    int*    redi  = (int*)(smem + 76544);

    const int tid  = threadIdx.x;
    const int bid  = blockIdx.x;
    const int b    = bid >> 6;
    const int t0   = (bid & 63) * 64;
    const int w    = tid >> 6;
    const int lane = tid & 63;
    const int tok  = tid >> 2;          // owner token (0..63)
    const int d0   = (tid & 3) * 64;    // owner dim base

    // ---- init: stage x into resf (coalesced), owners copy rows to registers
    const float* xb = x + (size_t)b * D * T + t0;
    for (int it = 0; it < 64; ++it) {
        const int lin = it * 256 + tid;
        const int tk = lin & 63, d = lin >> 6;
        resf[tk * 257 + d] = xb[(size_t)d * T + tk];
    }
    __syncthreads();
    float rr[64];
    #pragma unroll
    for (int i = 0; i < 64; ++i) rr[i] = resf[tok * 257 + d0 + i];
    __syncthreads();   // before union reuse as A planes

    double lacc = 0.0;

    for (int q = 0; q < NQ; ++q) {
        // ---- encode A hi/lo planes (XOR-swizzled 16B units)
        {
            const int swz = (tok & 7) << 4;
            #pragma unroll
            for (int c = 0; c < 8; ++c) {
                short8v h, l;
                #pragma unroll
                for (int j = 0; j < 8; ++j) {
                    const float v = rr[c * 8 + j];
                    const unsigned short hh = f2bf(v);
                    h[j] = (short)hh;
                    l[j] = (short)f2bf(v - bf2f(hh));
                }
                const int byo = tok * 512 + ((d0 * 2 + c * 16) ^ swz);
                *(short8v*)(smc + byo) = h;
                *(short8v*)(smc + 32768 + byo) = l;
            }
        }
        for (int i = tid; i < BINS; i += 256) norms[i] = cbnf[q * BINS + i];
        __syncthreads();

        // ---- distance scan via MFMA
        float bv1[16], bv2[16]; int bi1[16];
        #pragma unroll
        for (int s = 0; s < 16; ++s) { bv1[s] = 3.4e38f; bv2[s] = 3.4e38f; bi1[s] = 0; }

        const unsigned short* bqh = bfh + (size_t)q * 512 * 512;
        const unsigned short* bql = bfl + (size_t)q * 512 * 512;
        const int dbase = (lane >> 4) * 16;
        const int col   = lane & 15;

        #pragma unroll 1
        for (int nt = 0; nt < 16; ++nt) {
            const int ntg = w * 16 + nt;
            float4v acc0 = {0,0,0,0}, acc1 = {0,0,0,0}, acc2 = {0,0,0,0}, acc3 = {0,0,0,0};
            const unsigned short* ph = bqh + ((size_t)ntg * 8) * 512 + lane * 8;
            const unsigned short* pl = bql + ((size_t)ntg * 8) * 512 + lane * 8;
            #pragma unroll
            for (int ks = 0; ks < 8; ++ks) {
                const short8v Bh = *(const short8v*)(ph + ks * 512);
                const short8v Bl = *(const short8v*)(pl + ks * 512);
                const int dby = ks * 64 + dbase;
                #define MTSTEP(MT, ACC) { \
                    const int tk_ = MT * 16 + col; \
                    const int byo_ = tk_ * 512 + (dby ^ ((tk_ & 7) << 4)); \
                    const short8v Ah = *(const short8v*)(smc + byo_); \
                    const short8v Al = *(const short8v*)(smc + 32768 + byo_); \
                    ACC = __builtin_amdgcn_mfma_f32_16x16x32_bf16(Al, Bh, ACC, 0, 0, 0); \
                    ACC = __builtin_amdgcn_mfma_f32_16x16x32_bf16(Ah, Bl, ACC, 0, 0, 0); \
                    ACC = __builtin_amdgcn_mfma_f32_16x16x32_bf16(Ah, Bh, ACC, 0, 0, 0); }
                MTSTEP(0, acc0) MTSTEP(1, acc1) MTSTEP(2, acc2) MTSTEP(3, acc3)
                #undef MTSTEP
            }
            const float qn  = norms[ntg * 16 + col];
            const int   bin = ntg * 16 + col;
            #define EPI(MT, ACC) { \
                _Pragma("unroll") \
                for (int r = 0; r < 4; ++r) { \
                    const float s = fmaf(-2.0f, ACC[r], qn); \
                    const int sl = MT * 4 + r; \
                    if (s < bv1[sl]) { bv2[sl] = bv1[sl]; bv1[sl] = s; bi1[sl] = bin; } \
                    else if (s < bv2[sl]) bv2[sl] = s; } }
            EPI(0, acc0) EPI(1, acc1) EPI(2, acc2) EPI(3, acc3)
            #undef EPI
        }

        // ---- top-2 merge across the 16 cols (lanes rg*16..rg*16+15), index tiebreak
        #pragma unroll
        for (int off = 1; off <= 8; off <<= 1) {
            #pragma unroll
            for (int sl = 0; sl < 16; ++sl) {
                const float ov1 = __shfl_xor(bv1[sl], off, 64);
                const float ov2 = __shfl_xor(bv2[sl], off, 64);
                const int   oi  = __shfl_xor(bi1[sl], off, 64);
                if (ov1 < bv1[sl] || (ov1 == bv1[sl] && oi < bi1[sl])) {
                    bv2[sl] = fminf(bv1[sl], ov2); bv1[sl] = ov1; bi1[sl] = oi;
                } else {
                    bv2[sl] = fminf(bv2[sl], ov1);
                }
            }
        }
        if ((lane & 15) == 0) {
            const int rg = lane >> 4;
            #pragma unroll
            for (int mt = 0; mt < 4; ++mt)
                #pragma unroll
                for (int r = 0; r < 4; ++r) {
                    const int tk = mt * 16 + rg * 4 + r;
                    const int sl = mt * 4 + r;
                    mg1[tk * 4 + w] = bv1[sl];
                    mg2[tk * 4 + w] = bv2[sl];
                    mgi[tk * 4 + w] = bi1[sl];
                }
        }
        __syncthreads();

        if (tid < 64) {
            float g1 = mg1[tid*4], g2 = mg2[tid*4]; int gi = mgi[tid*4];
            #pragma unroll
            for (int wv = 1; wv < 4; ++wv) {
                const float v1 = mg1[tid*4+wv], v2 = mg2[tid*4+wv];
                const int   i1 = mgi[tid*4+wv];
                if (v1 < g1 || (v1 == g1 && i1 < gi)) { g2 = fminf(g1, v2); g1 = v1; gi = i1; }
                else g2 = fminf(g2, v1);
            }
            idxsL[tid]  = gi;
            flagsL[tid] = (g2 - g1 < 0.008f) ? 1 : 0;   // EPS >= 8x split-bf16 error bound
        }
        __syncthreads();

        // ---- exact f64 fallback for near ties (rare)
        const float* cbq = cb + (size_t)q * BINS * D;
        for (int tk2 = 0; tk2 < 64; ++tk2) {
            if (!flagsL[tk2]) continue;                  // uniform (LDS)
            if (tok == tk2) {
                #pragma unroll
                for (int i = 0; i < 64; ++i) fbres[d0 + i] = rr[i];
            }
            __syncthreads();
            double bb = 1e300; int bbi = 0;
            #pragma unroll
            for (int jj = 0; jj < 4; ++jj) {
                const int bin = tid + 256 * jj;          // ascending -> lowest-idx kept
                const float* crow = cbq + (size_t)bin * D;
                double a = 0.0;
                for (int d = 0; d < D; d += 4) {
                    const float4 rv = *(const float4*)&fbres[d];   // broadcast
                    const float4 cv = *(const float4*)&crow[d];
                    a = fma((double)rv.x, (double)cv.x, a);
                    a = fma((double)rv.y, (double)cv.y, a);
                    a = fma((double)rv.z, (double)cv.z, a);
                    a = fma((double)rv.w, (double)cv.w, a);
                }
                const double s = fma(-2.0, a, cbn[q * BINS + bin]);
                if (s < bb) { bb = s; bbi = bin; }
            }
            redv[tid] = bb; redi[tid] = bbi;
            __syncthreads();
            for (int s2 = 128; s2 >= 1; s2 >>= 1) {
                if (tid < s2) {
                    const double ov = redv[tid + s2]; const int oi = redi[tid + s2];
                    if (ov < redv[tid] || (ov == redv[tid] && oi < redi[tid])) {
                        redv[tid] = ov; redi[tid] = oi;
                    }
                }
                __syncthreads();
            }
            if (tid == 0) idxsL[tk2] = redi[0];
            __syncthreads();
        }

        // codes (final idx)
        if (tid < 64)
            out[OFF_C + (size_t)q * B * T + (size_t)b * T + t0 + tid] = (float)idxsL[tid];

        // ---- faithful f32 straight-through update (owners)
        {
            const int myidx = idxsL[tok];
            const float* crow = cbq + (size_t)myidx * D + d0;
            #pragma unroll
            for (int i = 0; i < 64; i += 4) {
                const float4 qv = *(const float4*)(crow + i);
                float e, qst, dd;
                e = qv.x - rr[i];   qst = rr[i]   + e; dd = qst - rr[i];
                lacc = fma((double)dd, (double)dd, lacc); rr[i]   -= qst;
                e = qv.y - rr[i+1]; qst = rr[i+1] + e; dd = qst - rr[i+1];
                lacc = fma((double)dd, (double)dd, lacc); rr[i+1] -= qst;
                e = qv.z - rr[i+2]; qst = rr[i+2] + e; dd = qst - rr[i+2];
                lacc = fma((double)dd, (double)dd, lacc); rr[i+2] -= qst;
                e = qv.w - rr[i+3]; qst = rr[i+3] + e; dd = qst - rr[i+3];
                lacc = fma((double)dd, (double)dd, lacc); rr[i+3] -= qst;
            }
        }
    } // q

    // ---- final: quantized = x - res_final (union reused as resf)
    __syncthreads();
    #pragma unroll
    for (int i = 0; i < 64; ++i) resf[tok * 257 + d0 + i] = rr[i];
    __syncthreads();
    float* ob = out + (size_t)b * D * T + t0;
    for (int it = 0; it < 64; ++it) {
        const int lin = it * 256 + tid;
        const int tk = lin & 63, d = lin >> 6;
        ob[(size_t)d * T + tk] = xb[(size_t)d * T + tk] - resf[tk * 257 + d];
    }

    // ---- deterministic loss partial
    redv[tid] = lacc;
    __syncthreads();
    for (int s2 = 128; s2 >= 1; s2 >>= 1) {
        if (tid < s2) redv[tid] += redv[tid + s2];
        __syncthreads();
    }
    if (tid == 0) lpart[bid] = redv[0];
}

// ---------------- OLD PATH (R2, known-good) kept as ws-size fallback ----------------
#define OTOK 32
#define ORS 260
__global__ __launch_bounds__(256, 3) void rvq_main_old(
    const float* __restrict__ x, const float* __restrict__ cb,
    const double* __restrict__ cbn, const float* __restrict__ cbnf,
    float* __restrict__ out, double* __restrict__ lpart)
{
    __shared__ float  res[OTOK][ORS];
    __shared__ float  bv1s[OTOK][16];
    __shared__ float  bv2s[OTOK][16];
    __shared__ int    bi1s[OTOK][16];
    __shared__ int    idxs[OTOK];
    __shared__ int    flags[OTOK];
    __shared__ double fbv[256];
    __shared__ int    fbi[256];

    const int tid = threadIdx.x;
    const int bid = blockIdx.x;
    const int b  = bid >> 7;
    const int t0 = (bid & 127) * OTOK;

    const float* xb = x + (size_t)b * D * T + t0;
    #pragma unroll
    for (int it = 0; it < 32; ++it) {
        const int d  = it * 8 + (tid >> 5);
        const int tk = tid & 31;
        res[tk][d] = xb[(size_t)d * T + tk];
    }
    __syncthreads();

    float qreg[32];
    #pragma unroll
    for (int i = 0; i < 32; ++i) qreg[i] = 0.0f;

    const int tg = tid & 15;
    const int bg = tid >> 4;
    const int tku = tid >> 3;
    const int d0u = (tid & 7) * 32;
    double lacc = 0.0;

    for (int q = 0; q < NQ; ++q) {
        const float*  cbq = cb   + (size_t)q * BINS * D;
        const float*  cnf = cbnf + (size_t)q * BINS;
        const double* cnd = cbn  + (size_t)q * BINS;

        float bvA = 3.4e38f, bvA2 = 3.4e38f;  int biA = 0;
        float bvB = 3.4e38f, bvB2 = 3.4e38f;  int biB = 0;

        for (int iter = 0; iter < 8; ++iter) {
            const int binbase = iter * 128 + bg * 8;
            float a0[8], a1[8];
            #pragma unroll
            for (int j = 0; j < 8; ++j) { a0[j] = 0.0f; a1[j] = 0.0f; }
            for (int d = 0; d < D; d += 4) {
                const float4 r0 = *(const float4*)&res[tg][d];
                const float4 r1 = *(const float4*)&res[tg + 16][d];
                #pragma unroll
                for (int j = 0; j < 8; ++j) {
                    const float4 c = *(const float4*)&cbq[(size_t)(binbase + j) * D + d];
                    a0[j] = fmaf(r0.x, c.x, a0[j]); a0[j] = fmaf(r0.y, c.y, a0[j]);
                    a0[j] = fmaf(r0.z, c.z, a0[j]); a0[j] = fmaf(r0.w, c.w, a0[j]);
                    a1[j] = fmaf(r1.x, c.x, a1[j]); a1[j] = fmaf(r1.y, c.y, a1[j]);
                    a1[j] = fmaf(r1.z, c.z, a1[j]); a1[j] = fmaf(r1.w, c.w, a1[j]);
                }
            }
            #pragma unroll
            for (int j = 0; j < 8; ++j) {
                const int bin = binbase + j;
                const float qn = cnf[bin];
                const float s0 = fmaf(-2.0f, a0[j], qn);
                const float s1 = fmaf(-2.0f, a1[j], qn);
                if (s0 < bvA) { bvA2 = bvA; bvA = s0; biA = bin; }
                else if (s0 < bvA2) { bvA2 = s0; }
                if (s1 < bvB) { bvB2 = bvB; bvB = s1; biB = bin; }
                else if (s1 < bvB2) { bvB2 = s1; }
            }
        }
        bv1s[tg][bg]      = bvA;  bv2s[tg][bg]      = bvA2;  bi1s[tg][bg]      = biA;
        bv1s[tg + 16][bg] = bvB;  bv2s[tg + 16][bg] = bvB2;  bi1s[tg + 16][bg] = biB;
        __syncthreads();

        if (tid < OTOK) {
            float g1 = bv1s[tid][0], g2 = bv2s[tid][0];
            int   gi = bi1s[tid][0];
            #pragma unroll
            for (int g = 1; g < 16; ++g) {
                const float v1 = bv1s[tid][g];
                const float v2 = bv2s[tid][g];
                const int   i1 = bi1s[tid][g];
                if (v1 < g1 || (v1 == g1 && i1 < gi)) { g2 = fminf(g1, v2); g1 = v1; gi = i1; }
                else g2 = fminf(g2, v1);
            }
            idxs[tid]  = gi;
            flags[tid] = (g2 - g1 < 0.02f) ? 1 : 0;
        }
        __syncthreads();

        for (int tok = 0; tok < OTOK; ++tok) {
            if (!flags[tok]) continue;
            double bb = 1e300; int bbi = 0;
            #pragma unroll
            for (int jj = 0; jj < 4; ++jj) {
                const int bin = tid + 256 * jj;
                const float* crow = cbq + (size_t)bin * D;
                double a = 0.0;
                for (int d = 0; d < D; d += 4) {
                    const float4 r = *(const float4*)&res[tok][d];
                    const float4 c = *(const float4*)&crow[d];
                    a = fma((double)r.x, (double)c.x, a);
                    a = fma((double)r.y, (double)c.y, a);
                    a = fma((double)r.z, (double)c.z, a);
                    a = fma((double)r.w, (double)c.w, a);
                }
                const double s = fma(-2.0, a, cnd[bin]);
                if (s < bb) { bb = s; bbi = bin; }
            }
            fbv[tid] = bb; fbi[tid] = bbi;
            __syncthreads();
            for (int s2 = 128; s2 >= 1; s2 >>= 1) {
                if (tid < s2) {
                    const double ov = fbv[tid + s2]; const int oi = fbi[tid + s2];
                    const double mv = fbv[tid];      const int mi = fbi[tid];
                    if (ov < mv || (ov == mv && oi < mi)) { fbv[tid] = ov; fbi[tid] = oi; }
                }
                __syncthreads();
            }
            if (tid == 0) idxs[tok] = fbi[0];
            __syncthreads();
        }

        if (tid < OTOK)
            out[OFF_C + (size_t)q * B * T + (size_t)b * T + t0 + tid] = (float)idxs[tid];

        const float* crow = cbq + (size_t)idxs[tku] * D;
        #pragma unroll
        for (int i = 0; i < 8; ++i) {
            const int d = d0u + i * 4;
            const float4 qv = *(const float4*)&crow[d];
            float4 r = *(float4*)&res[tku][d];
            float e, qst, dd;
            e = qv.x - r.x; qst = r.x + e; dd = qst - r.x;
            lacc = fma((double)dd, (double)dd, lacc); qreg[i*4+0] += qst; r.x = r.x - qst;
            e = qv.y - r.y; qst = r.y + e; dd = qst - r.y;
            lacc = fma((double)dd, (double)dd, lacc); qreg[i*4+1] += qst; r.y = r.y - qst;
            e = qv.z - r.z; qst = r.z + e; dd = qst - r.z;
            lacc = fma((double)dd, (double)dd, lacc); qreg[i*4+2] += qst; r.z = r.z - qst;
            e = qv.w - r.w; qst = r.w + e; dd = qst - r.w;
            lacc = fma((double)dd, (double)dd, lacc); qreg[i*4+3] += qst; r.w = r.w - qst;
            *(float4*)&res[tku][d] = r;
        }
        __syncthreads();
    }

    #pragma unroll
    for (int i = 0; i < 8; ++i)
        *(float4*)&res[tku][d0u + i * 4] = *(float4*)&qreg[i * 4];
    __syncthreads();
    #pragma unroll
    for (int it = 0; it < 32; ++it) {
        const int d  = it * 8 + (tid >> 5);
        const int tk = tid & 31;
        out[(size_t)b * D * T + (size_t)d * T + t0 + tk] = res[tk][d];
    }

    fbv[tid] = lacc;
    __syncthreads();
    for (int s2 = 128; s2 >= 1; s2 >>= 1) {
        if (tid < s2) fbv[tid] += fbv[tid + s2];
        __syncthreads();
    }
    if (tid == 0) lpart[bid] = fbv[0];
}

// ---------------- finalize: loss mean + bandwidth scalar ----------------
__global__ __launch_bounds__(256) void finalize_kernel(
    const double* __restrict__ lpart, int nblk,
    const int* __restrict__ srp, float* __restrict__ out)
{
    __shared__ double sh[256];
    double a = 0.0;
    for (int i = threadIdx.x; i < nblk; i += 256) a += lpart[i];
    sh[threadIdx.x] = a;
    __syncthreads();
    for (int s = 128; s >= 1; s >>= 1) {
        if (threadIdx.x < s) sh[threadIdx.x] += sh[threadIdx.x + s];
        __syncthreads();
    }
    if (threadIdx.x == 0) {
        out[OFF_L]  = (float)(sh[0] / ((double)NQ * B * T * D));
        out[OFF_BW] = (float)((double)NQ * 10.0 * (double)srp[0] / 1000.0);
    }
}

extern "C" void kernel_launch(void* const* d_in, const int* in_sizes, int n_in,
                              void* d_out, int out_size, void* d_ws, size_t ws_size,
                              hipStream_t stream)
{
    const float* x  = (const float*)d_in[0];
    const float* cb = (const float*)d_in[1];
    const int*   sr = (const int*)d_in[2];
    float* out = (float*)d_out;

    // ws layout: cbn f64[8192] @0 | lpart f64[1024] @65536 | cbnf f32[8192] @73728
    //            bfh u16 @106496 (4 MiB) | bfl u16 @4300800 ... total 8495104 B
    double* cbn   = (double*)d_ws;
    double* lpart = (double*)((char*)d_ws + 65536);
    float*  cbnf  = (float*)((char*)d_ws + 73728);
    unsigned short* bfh = (unsigned short*)((char*)d_ws + 106496);
    unsigned short* bfl = (unsigned short*)((char*)d_ws + 106496 + 4194304);

    hipLaunchKernelGGL(cbnorm_kernel, dim3(NQ * BINS / 4), dim3(256), 0, stream, cb, cbn, cbnf);

    if (ws_size >= (size_t)8495104) {
        hipLaunchKernelGGL(prep_bfrag, dim3(1024), dim3(256), 0, stream, cb, bfh, bfl);
        hipLaunchKernelGGL(rvq_mfma, dim3(B * (T / 64)), dim3(256), 0, stream,
                           x, cb, cbn, cbnf, bfh, bfl, out, lpart);
        hipLaunchKernelGGL(finalize_kernel, dim3(1), dim3(256), 0, stream,
                           lpart, B * (T / 64), sr, out);
    } else {
        hipLaunchKernelGGL(rvq_main_old, dim3(B * (T / OTOK)), dim3(256), 0, stream,
                           x, cb, cbn, cbnf, out, lpart);
        hipLaunchKernelGGL(finalize_kernel, dim3(1), dim3(256), 0, stream,
                           lpart, B * (T / OTOK), sr, out);
    }
}